// Round 12
// baseline (575.257 us; speedup 1.0000x reference)
//
#include <hip/hip_runtime.h>
#include <hip/hip_bf16.h>
#include <stdint.h>

// B=8, N=1024, I=256, O=256, R=8
// out[b,dst,o] = (sum_{src,r} adj[b,src,dst,r] * f[b,src,r,o]) / clip(sum adj, 1e-16)
//
//  prep : x fp32->bf16; weight -> W_t[o*8+r][i] bf16
//  k1   : f_t[b][o][k=src*8+r] = W_t @ x^T (8B vector stores)
//  k2   : pout = adj^T @ f_t. MT=64 x NT=128, KS=2 -> 512 blocks x 512 thr
//         (8 waves 2m x 4o), KT=64, 2 blocks/CU, LDS = B-only 3x16KB.
//         R11->R12: (a) native __float2bfloat16 (compiler emits v_cvt_pk_bf16_f32;
//         hand bit-RNE cost ~45us of VALU in R11); (b) cvt is an explicit pipeline
//         stage: step kt = {issue B(kt+2)+A(kt+2); cvt A(kt+1) [full-step cover];
//         compute(kt); vmcnt(10)+s_barrier+sched_barrier(0)}. sched_barrier pins
//         step boundaries so the compiler can't hoist cvt next to the loads
//         (R11: VGPR=64 proved it did, destroying A's latency cover).
//         vmcnt(10) = this step's own batch -> order-safe like R8's vmcnt(4).
//  k3   : sum split-K partials, normalize.

typedef float          floatx4  __attribute__((ext_vector_type(4)));
typedef short          shortx8  __attribute__((ext_vector_type(8)));
typedef unsigned short ushortx4 __attribute__((ext_vector_type(4)));
typedef unsigned short ushortx8 __attribute__((ext_vector_type(8)));

__device__ __forceinline__ unsigned short f2bf(float f) {   // native RNE cast
  __hip_bfloat16 h = __float2bfloat16(f);
  unsigned short u; __builtin_memcpy(&u, &h, 2);
  return u;
}

__device__ __forceinline__ shortx8 cvt8(float4 a, float4 b) {
  union { unsigned short us[8]; shortx8 s; } r;
  r.us[0] = f2bf(a.x); r.us[1] = f2bf(a.y); r.us[2] = f2bf(a.z); r.us[3] = f2bf(a.w);
  r.us[4] = f2bf(b.x); r.us[5] = f2bf(b.y); r.us[6] = f2bf(b.z); r.us[7] = f2bf(b.w);
  return r.s;
}

__device__ __forceinline__ void gload16(const void* g, void* l) {
  __builtin_amdgcn_global_load_lds((__attribute__((address_space(1))) void*)g,
                                   (__attribute__((address_space(3))) void*)l,
                                   16, 0, 0);
}

// ---------------- merged prep ----------------
__global__ __launch_bounds__(256) void prep_xw(const float* __restrict__ x,
                                               const float* __restrict__ w,
                                               unsigned short* __restrict__ xbf,
                                               unsigned short* __restrict__ wt) {
  int bid = blockIdx.x;
  if (bid < 1024) {                                // x: 262144 threads x 8 elems
    int t = bid * 256 + threadIdx.x;
    const float4* p = (const float4*)x + (size_t)t * 2;
    float4 a = p[0], b4 = p[1];
    ushortx8 o;
    o[0] = f2bf(a.x);  o[1] = f2bf(a.y);  o[2] = f2bf(a.z);  o[3] = f2bf(a.w);
    o[4] = f2bf(b4.x); o[5] = f2bf(b4.y); o[6] = f2bf(b4.z); o[7] = f2bf(b4.w);
    *(ushortx8*)(xbf + (size_t)t * 8) = o;
  } else {                                         // w: 524288 scalar
    int id = (bid - 1024) * 256 + threadIdx.x;
    int r = id >> 16, i = (id >> 8) & 255, o = id & 255;
    float v = w[((size_t)(r * 256 + i) << 8) + o];
    wt[((size_t)(o * 8 + r) << 8) + i] = f2bf(v);
  }
}

// ---------------- kernel 1: f_t = x @ W (operand-swapped) ----------------
__global__ __launch_bounds__(256) void k1_gemm(const unsigned short* __restrict__ xbf,
                                               const unsigned short* __restrict__ wt,
                                               unsigned short* __restrict__ ft) {
  int bid = blockIdx.x;                            // 16 p-tiles x 64 q-tiles
  int p0 = (bid & 15) * 128, q0 = (bid >> 4) * 128;
  int l = threadIdx.x & 63, w = threadIdx.x >> 6;
  int lr = l & 15, lg = l >> 4;
  int pw = p0 + (w >> 1) * 64, qw = q0 + (w & 1) * 64;

  floatx4 acc[4][4] = {};
#pragma unroll
  for (int ks = 0; ks < 8; ++ks) {                 // K = 256 = 8 * 32
    shortx8 a[4], b[4];
#pragma unroll
    for (int pi = 0; pi < 4; ++pi)
      a[pi] = *(const shortx8*)(wt + (size_t)(pw + pi * 16 + lr) * 256 + ks * 32 + lg * 8);
#pragma unroll
    for (int qi = 0; qi < 4; ++qi)
      b[qi] = *(const shortx8*)(xbf + (size_t)(qw + qi * 16 + lr) * 256 + ks * 32 + lg * 8);
#pragma unroll
    for (int pi = 0; pi < 4; ++pi)
#pragma unroll
      for (int qi = 0; qi < 4; ++qi)
        acc[pi][qi] = __builtin_amdgcn_mfma_f32_16x16x32_bf16(a[pi], b[qi], acc[pi][qi], 0, 0, 0);
  }
  // row(n') = pw+pi*16+lg*4+reg -> (o, r); col(m) = qw+qi*16+lr -> (b8, src)
#pragma unroll
  for (int pi = 0; pi < 4; ++pi) {
    int nbase = pw + pi * 16 + lg * 4;
    int o = nbase >> 3, rb = nbase & 7;
#pragma unroll
    for (int qi = 0; qi < 4; ++qi) {
      int m = qw + qi * 16 + lr;
      int b8 = m >> 10, src = m & 1023;
      ushortx4 h;
      h[0] = f2bf(acc[pi][qi][0]); h[1] = f2bf(acc[pi][qi][1]);
      h[2] = f2bf(acc[pi][qi][2]); h[3] = f2bf(acc[pi][qi][3]);
      *(ushortx4*)(ft + ((size_t)(b8 * 256 + o) << 13) + src * 8 + rb) = h;
    }
  }
}

// ---------------- kernel 2: pout = adj^T @ f_t (+ denom) ----------------
// 512 blocks x 512 thr (8 waves, 2m x 4o). Block: b, 64 dst, 128 o, K-half.
#define BSZ (128 * 64)    // 16KB per B buffer (shorts)
__global__ __launch_bounds__(512, 4) void k2_gemm(const float* __restrict__ adj,
                                                  const unsigned short* __restrict__ ft,
                                                  float* __restrict__ pout,
                                                  float* __restrict__ dpart) {
  __shared__ __align__(16) unsigned short Blds[3 * BSZ];  // 48KB (B only)

  int bid = blockIdx.x;
  int b = bid & 7;                     // XCD pin
  int o0 = ((bid >> 3) & 1) * 128;     // 2 o-tiles (pair shares adj slice on one XCD)
  int kc = (bid >> 4) & 1;             // split-K half
  int dst0 = (bid >> 5) * 64;          // 16 dst-tiles

  int t = threadIdx.x, l = t & 63, w = t >> 6;     // 8 waves
  int lr = l & 15, lg = l >> 4;
  int wm = w >> 2, wo = w & 3;                     // wave -> (dst-half, o-quarter)
  bool wq0 = (wo == 0);                            // denom-owning waves (w=0, w=4)

  const int src_base = kc * 512;
  // A direct addressing: frag(mi,s,j) for lane (lr,lg):
  //   src = src_base + kt*8 + s*4 + lg ; dst = dst0 + wm*32 + mi*16 + lr ; r = j*4..+4
  const float* adjp = adj + ((size_t)b << 23) + ((size_t)src_base << 13)
                    + ((size_t)(dst0 + wm * 32 + lr) << 3) + ((size_t)lg << 13);
  const unsigned short* ftb = ft + ((size_t)b << 21);

  float dd[2] = {0.f, 0.f};            // denom partials (rows mi*16+lr), wq0 only
  floatx4 acc[2][2] = {};
  float4 aR0[2][2][2], aR1[2][2][2];   // fp32 A in flight [mi][s][j], alternating
  shortx8 afE[2][2], afO[2][2];        // bf16 A frags [s][mi], even/odd kt

  auto A_load = [&](int kt, float4 (&v)[2][2][2]) {
#pragma unroll
    for (int mi = 0; mi < 2; ++mi)
#pragma unroll
      for (int s = 0; s < 2; ++s)
#pragma unroll
        for (int j = 0; j < 2; ++j)
          v[mi][s][j] = *(const float4*)(adjp + (size_t)kt * 65536
                                         + s * 32768 + mi * 128 + j * 4);
  };
  auto A_cvt = [&](float4 (&v)[2][2][2], shortx8 (&af)[2][2]) {
#pragma unroll
    for (int mi = 0; mi < 2; ++mi)
#pragma unroll
      for (int s = 0; s < 2; ++s) {
        float4 p = v[mi][s][0], q = v[mi][s][1];
        af[s][mi] = cvt8(p, q);
        if (wq0) dd[mi] += ((p.x + p.y) + (p.z + p.w)) + ((q.x + q.y) + (q.z + q.w));
      }
  };
  auto B_stage = [&](int kt, int buf) {            // 2 gload16/wave, rows w*16..+15
    int kbase = (src_base + kt * 8) * 8;
    int csw = (l & 7) ^ (l >> 3);                  // pre-swizzled source chunk
#pragma unroll
    for (int i = 0; i < 2; ++i) {
      int orow = w * 16 + i * 8 + (l >> 3);
      const unsigned short* g = ftb + ((size_t)(o0 + orow) << 13) + kbase + (csw << 3);
      gload16(g, &Blds[buf * BSZ + (w * 16 + i * 8) * 64]);
    }
  };
  auto compute = [&](int buf, shortx8 (&af)[2][2]) {
#pragma unroll
    for (int s = 0; s < 2; ++s) {
      int slotbase = s * 4 + lg;
      shortx8 bfr[2];
#pragma unroll
      for (int ni = 0; ni < 2; ++ni) {
        int brow = wo * 32 + ni * 16 + lr;
        bfr[ni] = *(const shortx8*)&Blds[buf * BSZ + brow * 64 + ((slotbase ^ (brow & 7)) << 3)];
      }
#pragma unroll
      for (int mi = 0; mi < 2; ++mi)
#pragma unroll
        for (int ni = 0; ni < 2; ++ni)
          acc[mi][ni] = __builtin_amdgcn_mfma_f32_16x16x32_bf16(af[s][mi], bfr[ni], acc[mi][ni], 0, 0, 0);
    }
  };

// step kt: issue B(kt+2)->STG, A(kt+2)->AROUT; cvt A(kt+1) (ARIN->AFN); compute(CUR, AFC)
#define STEP(kt, CUR, STG, AFC, AFN, ARIN, AROUT, ISS, CVT, ST)        \
  {                                                                    \
    if (ISS) { B_stage((kt) + 2, STG); A_load((kt) + 2, AROUT); }      \
    if (CVT) A_cvt(ARIN, AFN);                                         \
    compute(CUR, AFC);                                                 \
    if (ST) {                                                          \
      if (ISS) { asm volatile("s_waitcnt vmcnt(10)" ::: "memory"); }   \
      else     { asm volatile("s_waitcnt vmcnt(0)"  ::: "memory"); }   \
      __builtin_amdgcn_s_barrier();                                    \
      __builtin_amdgcn_sched_barrier(0);                               \
    }                                                                  \
  }

  // ---- prologue: B(0),A(0),A(1),B(1); cvt A(0)->afE; keep newest 10 in flight ----
  B_stage(0, 0);
  A_load(0, aR0);
  A_load(1, aR1);
  B_stage(1, 1);
  A_cvt(aR0, afE);                     // compiler waits A(0); A(1)+B(1)=10 stay in flight
  asm volatile("s_waitcnt vmcnt(10)" ::: "memory");
  __builtin_amdgcn_s_barrier();
  __builtin_amdgcn_sched_barrier(0);

  // ---- main loop: kt 0..59 in 6-step macro (buf period 3 x parity 2) ----
  for (int kt0 = 0; kt0 < 60; kt0 += 6) {
    STEP(kt0 + 0, 0, 2, afE, afO, aR1, aR0, 1, 1, 1);
    STEP(kt0 + 1, 1, 0, afO, afE, aR0, aR1, 1, 1, 1);
    STEP(kt0 + 2, 2, 1, afE, afO, aR1, aR0, 1, 1, 1);
    STEP(kt0 + 3, 0, 2, afO, afE, aR0, aR1, 1, 1, 1);
    STEP(kt0 + 4, 1, 0, afE, afO, aR1, aR0, 1, 1, 1);
    STEP(kt0 + 5, 2, 1, afO, afE, aR0, aR1, 1, 1, 1);
  }
  // ---- tail: kt 60..63 ----
  STEP(60, 0, 2, afE, afO, aR1, aR0, 1, 1, 1);
  STEP(61, 1, 0, afO, afE, aR0, aR1, 1, 1, 1);
  STEP(62, 2, 1, afE, afO, aR1, aR0, 0, 1, 1);   // vmcnt(0): drains B(63)
  STEP(63, 0, 2, afO, afE, aR0, aR1, 0, 0, 0);
#undef STEP

  // ---- denom: in-register reduce over lg (lanes l, l^16, l^32, l^48) ----
  if (wq0) {
#pragma unroll
    for (int mi = 0; mi < 2; ++mi) {
      dd[mi] += __shfl_xor(dd[mi], 16);
      dd[mi] += __shfl_xor(dd[mi], 32);
    }
    if (l < 16) {
      dpart[kc * 8192 + (b << 10) + dst0 + wm * 32 + lr]      = dd[0];
      dpart[kc * 8192 + (b << 10) + dst0 + wm * 32 + 16 + lr] = dd[1];
    }
  }

  // ---- write partials ----
#pragma unroll
  for (int mi = 0; mi < 2; ++mi) {
#pragma unroll
    for (int reg = 0; reg < 4; ++reg) {
      int row = dst0 + wm * 32 + mi * 16 + lg * 4 + reg;
#pragma unroll
      for (int ni = 0; ni < 2; ++ni) {
        int col = o0 + wo * 32 + ni * 16 + lr;
        pout[(size_t)kc * 2097152 + (((size_t)b << 10) + row) * 256 + col] = acc[mi][ni][reg];
      }
    }
  }
}

// ---------------- kernel 3: split-K reduce + normalize ----------------
__global__ __launch_bounds__(256) void k3_reduce(const float* __restrict__ pout,
                                                 const float* __restrict__ dpart,
                                                 float* __restrict__ outp) {
  int bid = blockIdx.x;              // b*1024 + dst
  size_t base = (size_t)bid * 256 + threadIdx.x;
  float v = pout[base] + pout[2097152 + base];
  float d = dpart[bid] + dpart[8192 + bid];
  outp[base] = v / fmaxf(d, 1e-16f);
}

// ---------------- launch ----------------
extern "C" void kernel_launch(void* const* d_in, const int* in_sizes, int n_in,
                              void* d_out, int out_size, void* d_ws, size_t ws_size,
                              hipStream_t stream) {
  const float* x   = (const float*)d_in[0];
  const float* adj = (const float*)d_in[1];
  const float* w   = (const float*)d_in[2];
  float* out = (float*)d_out;

  char* ws = (char*)d_ws;
  unsigned short* ft  = (unsigned short*)(ws);              // 32 MB
  unsigned short* xbf = (unsigned short*)(ws + 33554432);   //  4 MB
  unsigned short* wt  = (unsigned short*)(ws + 37748736);   //  1 MB
  float* pout  = (float*)(ws + 38797312);                   // 16 MB
  float* dpart = (float*)(ws + 55574528);                   // 64 KB

  prep_xw<<<3072, 256, 0, stream>>>(x, w, xbf, wt);
  k1_gemm<<<1024, 256, 0, stream>>>(xbf, wt, ft);
  k2_gemm<<<512, 512, 0, stream>>>(adj, ft, pout, dpart);
  k3_reduce<<<8192, 256, 0, stream>>>(pout, dpart, out);
}

// Round 14
// 187.925 us; speedup vs baseline: 3.0611x; 3.0611x over previous
//
#include <hip/hip_runtime.h>
#include <hip/hip_bf16.h>
#include <stdint.h>

// B=8, N=1024, I=256, O=256, R=8
// out[b,dst,o] = (sum_{src,r} adj[b,src,dst,r] * f[b,src,r,o]) / clip(sum adj, 1e-16)
//
//  prep : x fp32->bf16; weight -> W_t[o*8+r][i] bf16
//  k1   : f_t[b][o][k=src*8+r] = W_t @ x^T (8B vector stores)
//  k2   : pout = adj^T @ f_t. MT=32 x NT=128, KS=2 -> 1024 blocks x 256 thr
//         (4 waves, 1m x 4o), KT=64, LDS 48KB (3 blocks/CU), VGPR<=128 via (256,4).
//         R13->R14: (a) GRID 512->1024 — R13 halved MT but kept grid, so dst
//         512..1023 was never written; k3 then divided 0xAA poison by ~1e-16
//         giving absmax 6048 (= 2*3.02e-13/1e-16, exact match). (b) prologue
//         fence vmcnt(12)->vmcnt(0): prologue loads aren't sched_barrier-pinned,
//         so the order-dependent count was unsafe (R10 lesson). Steady-state
//         vmcnt(12) IS safe: sched_barrier(0) ends each step, so the fence
//         drains exactly the previous step's batch under any within-step order.
//         A direct-to-reg (cvt at step start, 2-step-old regs, WAR reuse);
//         B via global_load_lds 3-buffer; no ds_write; reg denom.
//  k3   : sum split-K partials, normalize.

typedef float          floatx4  __attribute__((ext_vector_type(4)));
typedef short          shortx8  __attribute__((ext_vector_type(8)));
typedef unsigned short ushortx4 __attribute__((ext_vector_type(4)));
typedef unsigned short ushortx8 __attribute__((ext_vector_type(8)));

__device__ __forceinline__ unsigned short f2bf(float f) {   // native RNE cast
  __hip_bfloat16 h = __float2bfloat16(f);
  unsigned short u; __builtin_memcpy(&u, &h, 2);
  return u;
}

__device__ __forceinline__ shortx8 cvt8(float4 a, float4 b) {
  union { unsigned short us[8]; shortx8 s; } r;
  r.us[0] = f2bf(a.x); r.us[1] = f2bf(a.y); r.us[2] = f2bf(a.z); r.us[3] = f2bf(a.w);
  r.us[4] = f2bf(b.x); r.us[5] = f2bf(b.y); r.us[6] = f2bf(b.z); r.us[7] = f2bf(b.w);
  return r.s;
}

__device__ __forceinline__ void gload16(const void* g, void* l) {
  __builtin_amdgcn_global_load_lds((__attribute__((address_space(1))) void*)g,
                                   (__attribute__((address_space(3))) void*)l,
                                   16, 0, 0);
}

// ---------------- merged prep ----------------
__global__ __launch_bounds__(256) void prep_xw(const float* __restrict__ x,
                                               const float* __restrict__ w,
                                               unsigned short* __restrict__ xbf,
                                               unsigned short* __restrict__ wt) {
  int bid = blockIdx.x;
  if (bid < 1024) {                                // x: 262144 threads x 8 elems
    int t = bid * 256 + threadIdx.x;
    const float4* p = (const float4*)x + (size_t)t * 2;
    float4 a = p[0], b4 = p[1];
    ushortx8 o;
    o[0] = f2bf(a.x);  o[1] = f2bf(a.y);  o[2] = f2bf(a.z);  o[3] = f2bf(a.w);
    o[4] = f2bf(b4.x); o[5] = f2bf(b4.y); o[6] = f2bf(b4.z); o[7] = f2bf(b4.w);
    *(ushortx8*)(xbf + (size_t)t * 8) = o;
  } else {                                         // w: 524288 scalar
    int id = (bid - 1024) * 256 + threadIdx.x;
    int r = id >> 16, i = (id >> 8) & 255, o = id & 255;
    float v = w[((size_t)(r * 256 + i) << 8) + o];
    wt[((size_t)(o * 8 + r) << 8) + i] = f2bf(v);
  }
}

// ---------------- kernel 1: f_t = x @ W (operand-swapped) ----------------
__global__ __launch_bounds__(256) void k1_gemm(const unsigned short* __restrict__ xbf,
                                               const unsigned short* __restrict__ wt,
                                               unsigned short* __restrict__ ft) {
  int bid = blockIdx.x;                            // 16 p-tiles x 64 q-tiles
  int p0 = (bid & 15) * 128, q0 = (bid >> 4) * 128;
  int l = threadIdx.x & 63, w = threadIdx.x >> 6;
  int lr = l & 15, lg = l >> 4;
  int pw = p0 + (w >> 1) * 64, qw = q0 + (w & 1) * 64;

  floatx4 acc[4][4] = {};
#pragma unroll
  for (int ks = 0; ks < 8; ++ks) {                 // K = 256 = 8 * 32
    shortx8 a[4], b[4];
#pragma unroll
    for (int pi = 0; pi < 4; ++pi)
      a[pi] = *(const shortx8*)(wt + (size_t)(pw + pi * 16 + lr) * 256 + ks * 32 + lg * 8);
#pragma unroll
    for (int qi = 0; qi < 4; ++qi)
      b[qi] = *(const shortx8*)(xbf + (size_t)(qw + qi * 16 + lr) * 256 + ks * 32 + lg * 8);
#pragma unroll
    for (int pi = 0; pi < 4; ++pi)
#pragma unroll
      for (int qi = 0; qi < 4; ++qi)
        acc[pi][qi] = __builtin_amdgcn_mfma_f32_16x16x32_bf16(a[pi], b[qi], acc[pi][qi], 0, 0, 0);
  }
  // row(n') = pw+pi*16+lg*4+reg -> (o, r); col(m) = qw+qi*16+lr -> (b8, src)
#pragma unroll
  for (int pi = 0; pi < 4; ++pi) {
    int nbase = pw + pi * 16 + lg * 4;
    int o = nbase >> 3, rb = nbase & 7;
#pragma unroll
    for (int qi = 0; qi < 4; ++qi) {
      int m = qw + qi * 16 + lr;
      int b8 = m >> 10, src = m & 1023;
      ushortx4 h;
      h[0] = f2bf(acc[pi][qi][0]); h[1] = f2bf(acc[pi][qi][1]);
      h[2] = f2bf(acc[pi][qi][2]); h[3] = f2bf(acc[pi][qi][3]);
      *(ushortx4*)(ft + ((size_t)(b8 * 256 + o) << 13) + src * 8 + rb) = h;
    }
  }
}

// ---------------- kernel 2: pout = adj^T @ f_t (+ denom) ----------------
// 1024 blocks x 256 thr (4 waves, each one o-quarter). Block: b, 32 dst, 128 o, K-half.
#define BSZ (128 * 64)    // 16KB per B buffer (shorts)
__global__ __launch_bounds__(256, 4) void k2_gemm(const float* __restrict__ adj,
                                                  const unsigned short* __restrict__ ft,
                                                  float* __restrict__ pout,
                                                  float* __restrict__ dpart) {
  __shared__ __align__(16) unsigned short Blds[3 * BSZ];  // 48KB (B only)

  int bid = blockIdx.x;                // 1024 blocks: [dst(5)|kc(1)|o(1)|b(3)]
  int b = bid & 7;                     // XCD pin
  int o0 = ((bid >> 3) & 1) * 128;     // 2 o-tiles
  int kc = (bid >> 4) & 1;             // split-K half
  int dst0 = (bid >> 5) * 32;          // 32 dst-tiles (full N=1024)

  int t = threadIdx.x, l = t & 63, w = t >> 6;     // 4 waves, wave = o-quarter
  int lr = l & 15, lg = l >> 4;
  bool wq0 = (w == 0);                             // denom-owning wave

  const int src_base = kc * 512;
  // A direct addressing: frag(mi,s,j) for lane (lr,lg):
  //   src = src_base + kt*8 + s*4 + lg ; dst = dst0 + mi*16 + lr ; r = j*4..+4
  const float* adjp = adj + ((size_t)b << 23) + ((size_t)src_base << 13)
                    + ((size_t)(dst0 + lr) << 3) + ((size_t)lg << 13);
  const unsigned short* ftb = ft + ((size_t)b << 21);

  float dd[2] = {0.f, 0.f};            // denom partials (rows mi*16+lr), wq0 only
  floatx4 acc[2][2] = {};
  float4 aR0[2][2][2], aR1[2][2][2];   // fp32 A in flight [mi][s][j], kt-parity ping-pong

  auto A_load = [&](int kt, float4 (&v)[2][2][2]) {
#pragma unroll
    for (int mi = 0; mi < 2; ++mi)
#pragma unroll
      for (int s = 0; s < 2; ++s)
#pragma unroll
        for (int j = 0; j < 2; ++j)
          v[mi][s][j] = *(const float4*)(adjp + (size_t)kt * 65536
                                         + s * 32768 + mi * 128 + j * 4);
  };
  auto B_stage = [&](int kt, int buf) {            // 4 gload16/thread, rows w*32..+31
    int kbase = (src_base + kt * 8) * 8;
    int csw = (l & 7) ^ (l >> 3);                  // pre-swizzled source chunk
#pragma unroll
    for (int i = 0; i < 4; ++i) {
      int orow = w * 32 + i * 8 + (l >> 3);
      const unsigned short* g = ftb + ((size_t)(o0 + orow) << 13) + kbase + (csw << 3);
      gload16(g, &Blds[buf * BSZ + (w * 32 + i * 8) * 64]);
    }
  };

#define STEP(kt, CUR, STG, AR, ISS, ST)                                          \
  {                                                                              \
    if (ISS) B_stage((kt) + 2, STG);                                             \
    shortx8 af[2][2];                                                            \
    _Pragma("unroll") for (int mi = 0; mi < 2; ++mi)                             \
      _Pragma("unroll") for (int s = 0; s < 2; ++s) {                            \
        float4 p = AR[mi][s][0], q = AR[mi][s][1];                               \
        af[s][mi] = cvt8(p, q);                                                  \
        if (wq0) dd[mi] += ((p.x + p.y) + (p.z + p.w)) + ((q.x + q.y) + (q.z + q.w)); \
      }                                                                          \
    if (ISS) A_load((kt) + 2, AR);  /* WAR on AR: must follow cvt */             \
    _Pragma("unroll") for (int s = 0; s < 2; ++s) {                              \
      int slotbase = s * 4 + lg;                                                 \
      shortx8 bfr[2];                                                            \
      _Pragma("unroll") for (int ni = 0; ni < 2; ++ni) {                         \
        int brow = w * 32 + ni * 16 + lr;                                        \
        bfr[ni] = *(const shortx8*)&Blds[(CUR) * BSZ + brow * 64 + ((slotbase ^ (brow & 7)) << 3)]; \
      }                                                                          \
      _Pragma("unroll") for (int mi = 0; mi < 2; ++mi)                           \
        _Pragma("unroll") for (int ni = 0; ni < 2; ++ni)                         \
          acc[mi][ni] = __builtin_amdgcn_mfma_f32_16x16x32_bf16(af[s][mi], bfr[ni], acc[mi][ni], 0, 0, 0); \
    }                                                                            \
    if (ST) {                                                                    \
      if (ISS) { asm volatile("s_waitcnt vmcnt(12)" ::: "memory"); }             \
      else     { asm volatile("s_waitcnt vmcnt(0)"  ::: "memory"); }             \
      __builtin_amdgcn_s_barrier();                                              \
      __builtin_amdgcn_sched_barrier(0);                                         \
    }                                                                            \
  }

  // ---- prologue: B(0),A(0),A(1),B(1); FULL drain (order-safe, one-time) ----
  B_stage(0, 0);
  A_load(0, aR0);
  A_load(1, aR1);
  B_stage(1, 1);
  asm volatile("s_waitcnt vmcnt(0)" ::: "memory");
  __builtin_amdgcn_s_barrier();
  __builtin_amdgcn_sched_barrier(0);

  // ---- main loop: kt 0..59 in 6-step macro (buf period 3 x reg parity 2) ----
  for (int kt0 = 0; kt0 < 60; kt0 += 6) {
    STEP(kt0 + 0, 0, 2, aR0, 1, 1);
    STEP(kt0 + 1, 1, 0, aR1, 1, 1);
    STEP(kt0 + 2, 2, 1, aR0, 1, 1);
    STEP(kt0 + 3, 0, 2, aR1, 1, 1);
    STEP(kt0 + 4, 1, 0, aR0, 1, 1);
    STEP(kt0 + 5, 2, 1, aR1, 1, 1);
  }
  // ---- tail: kt 60..63 ----
  STEP(60, 0, 2, aR0, 1, 1);
  STEP(61, 1, 0, aR1, 1, 1);
  STEP(62, 2, 1, aR0, 0, 1);   // vmcnt(0): drains B(63)+A(63)
  STEP(63, 0, 2, aR1, 0, 0);
#undef STEP

  // ---- denom: in-register reduce over lg (lanes l, l^16, l^32, l^48) ----
  if (wq0) {
#pragma unroll
    for (int mi = 0; mi < 2; ++mi) {
      dd[mi] += __shfl_xor(dd[mi], 16);
      dd[mi] += __shfl_xor(dd[mi], 32);
    }
    if (l < 16) {
      dpart[kc * 8192 + (b << 10) + dst0 + lr]      = dd[0];
      dpart[kc * 8192 + (b << 10) + dst0 + 16 + lr] = dd[1];
    }
  }

  // ---- write partials ----
#pragma unroll
  for (int mi = 0; mi < 2; ++mi) {
#pragma unroll
    for (int reg = 0; reg < 4; ++reg) {
      int row = dst0 + mi * 16 + lg * 4 + reg;
#pragma unroll
      for (int ni = 0; ni < 2; ++ni) {
        int col = o0 + w * 32 + ni * 16 + lr;
        pout[(size_t)kc * 2097152 + (((size_t)b << 10) + row) * 256 + col] = acc[mi][ni][reg];
      }
    }
  }
}

// ---------------- kernel 3: split-K reduce + normalize ----------------
__global__ __launch_bounds__(256) void k3_reduce(const float* __restrict__ pout,
                                                 const float* __restrict__ dpart,
                                                 float* __restrict__ outp) {
  int bid = blockIdx.x;              // b*1024 + dst
  size_t base = (size_t)bid * 256 + threadIdx.x;
  float v = pout[base] + pout[2097152 + base];
  float d = dpart[bid] + dpart[8192 + bid];
  outp[base] = v / fmaxf(d, 1e-16f);
}

// ---------------- launch ----------------
extern "C" void kernel_launch(void* const* d_in, const int* in_sizes, int n_in,
                              void* d_out, int out_size, void* d_ws, size_t ws_size,
                              hipStream_t stream) {
  const float* x   = (const float*)d_in[0];
  const float* adj = (const float*)d_in[1];
  const float* w   = (const float*)d_in[2];
  float* out = (float*)d_out;

  char* ws = (char*)d_ws;
  unsigned short* ft  = (unsigned short*)(ws);              // 32 MB
  unsigned short* xbf = (unsigned short*)(ws + 33554432);   //  4 MB
  unsigned short* wt  = (unsigned short*)(ws + 37748736);   //  1 MB
  float* pout  = (float*)(ws + 38797312);                   // 16 MB
  float* dpart = (float*)(ws + 55574528);                   // 64 KB

  prep_xw<<<3072, 256, 0, stream>>>(x, w, xbf, wt);
  k1_gemm<<<1024, 256, 0, stream>>>(xbf, wt, ft);
  k2_gemm<<<1024, 256, 0, stream>>>(adj, ft, pout, dpart);
  k3_reduce<<<8192, 256, 0, stream>>>(pout, dpart, out);
}

// Round 15
// 134.349 us; speedup vs baseline: 4.2818x; 1.3988x over previous
//
#include <hip/hip_runtime.h>
#include <hip/hip_bf16.h>
#include <stdint.h>

// B=8, N=1024, I=256, O=256, R=8
// out[b,dst,o] = (sum_{src,r} adj[b,src,dst,r] * f[b,src,r,o]) / clip(sum adj, 1e-16)
//
//  prep : x fp32->bf16; weight -> W_t[o*8+r][i] bf16
//  k1   : f_t[b][o][k=src*8+r] = W_t @ x^T (8B vector stores)
//  k2   : R8 structure (best measured: k2~110us) with pipeline depth +1.
//         MT=64 x NT=128, KS=2 -> 512 blocks x 512 thr (8 waves 2m x 4o), KT=64.
//         A (adj): COALESCED reg-stage (32B/thread-pair) -> cvt -> ds_write,
//         2 reg sets + 2 LDS bufs, store A(kt+1) loaded 2 steps earlier
//         (cover 2.3 steps vs R8's 1.3 — R8's diagnosed limiter).
//         B (f_t): global_load_lds, 4 buffers, issue kt+3 (cover 2.7 steps).
//         Per-step batch = 4 vmem ops, sched_barrier-pinned; steady fence
//         vmcnt(8)+lgkmcnt(0) keeps exactly the last 2 steps in flight
//         (order-safe counted fence, R10 lesson). Tail 8->4->0.
//         LDS 80KB -> 2 blocks/CU. Native cvt (R12 lesson), fused fp32 denom.
//  k3   : sum split-K partials, normalize.

typedef float          floatx4  __attribute__((ext_vector_type(4)));
typedef short          shortx8  __attribute__((ext_vector_type(8)));
typedef unsigned short ushortx4 __attribute__((ext_vector_type(4)));
typedef unsigned short ushortx8 __attribute__((ext_vector_type(8)));

__device__ __forceinline__ unsigned short f2bf(float f) {   // native RNE cast
  __hip_bfloat16 h = __float2bfloat16(f);
  unsigned short u; __builtin_memcpy(&u, &h, 2);
  return u;
}

__device__ __forceinline__ void gload16(const void* g, void* l) {
  __builtin_amdgcn_global_load_lds((__attribute__((address_space(1))) void*)g,
                                   (__attribute__((address_space(3))) void*)l,
                                   16, 0, 0);
}

// ---------------- merged prep ----------------
__global__ __launch_bounds__(256) void prep_xw(const float* __restrict__ x,
                                               const float* __restrict__ w,
                                               unsigned short* __restrict__ xbf,
                                               unsigned short* __restrict__ wt) {
  int bid = blockIdx.x;
  if (bid < 1024) {                                // x: 262144 threads x 8 elems
    int t = bid * 256 + threadIdx.x;
    const float4* p = (const float4*)x + (size_t)t * 2;
    float4 a = p[0], b4 = p[1];
    ushortx8 o;
    o[0] = f2bf(a.x);  o[1] = f2bf(a.y);  o[2] = f2bf(a.z);  o[3] = f2bf(a.w);
    o[4] = f2bf(b4.x); o[5] = f2bf(b4.y); o[6] = f2bf(b4.z); o[7] = f2bf(b4.w);
    *(ushortx8*)(xbf + (size_t)t * 8) = o;
  } else {                                         // w: 524288 scalar
    int id = (bid - 1024) * 256 + threadIdx.x;
    int r = id >> 16, i = (id >> 8) & 255, o = id & 255;
    float v = w[((size_t)(r * 256 + i) << 8) + o];
    wt[((size_t)(o * 8 + r) << 8) + i] = f2bf(v);
  }
}

// ---------------- kernel 1: f_t = x @ W (operand-swapped) ----------------
__global__ __launch_bounds__(256) void k1_gemm(const unsigned short* __restrict__ xbf,
                                               const unsigned short* __restrict__ wt,
                                               unsigned short* __restrict__ ft) {
  int bid = blockIdx.x;                            // 16 p-tiles x 64 q-tiles
  int p0 = (bid & 15) * 128, q0 = (bid >> 4) * 128;
  int l = threadIdx.x & 63, w = threadIdx.x >> 6;
  int lr = l & 15, lg = l >> 4;
  int pw = p0 + (w >> 1) * 64, qw = q0 + (w & 1) * 64;

  floatx4 acc[4][4] = {};
#pragma unroll
  for (int ks = 0; ks < 8; ++ks) {                 // K = 256 = 8 * 32
    shortx8 a[4], b[4];
#pragma unroll
    for (int pi = 0; pi < 4; ++pi)
      a[pi] = *(const shortx8*)(wt + (size_t)(pw + pi * 16 + lr) * 256 + ks * 32 + lg * 8);
#pragma unroll
    for (int qi = 0; qi < 4; ++qi)
      b[qi] = *(const shortx8*)(xbf + (size_t)(qw + qi * 16 + lr) * 256 + ks * 32 + lg * 8);
#pragma unroll
    for (int pi = 0; pi < 4; ++pi)
#pragma unroll
      for (int qi = 0; qi < 4; ++qi)
        acc[pi][qi] = __builtin_amdgcn_mfma_f32_16x16x32_bf16(a[pi], b[qi], acc[pi][qi], 0, 0, 0);
  }
  // row(n') = pw+pi*16+lg*4+reg -> (o, r); col(m) = qw+qi*16+lr -> (b8, src)
#pragma unroll
  for (int pi = 0; pi < 4; ++pi) {
    int nbase = pw + pi * 16 + lg * 4;
    int o = nbase >> 3, rb = nbase & 7;
#pragma unroll
    for (int qi = 0; qi < 4; ++qi) {
      int m = qw + qi * 16 + lr;
      int b8 = m >> 10, src = m & 1023;
      ushortx4 h;
      h[0] = f2bf(acc[pi][qi][0]); h[1] = f2bf(acc[pi][qi][1]);
      h[2] = f2bf(acc[pi][qi][2]); h[3] = f2bf(acc[pi][qi][3]);
      *(ushortx4*)(ft + ((size_t)(b8 * 256 + o) << 13) + src * 8 + rb) = h;
    }
  }
}

// ---------------- kernel 2: pout = adj^T @ f_t (+ denom) ----------------
// 512 blocks x 512 thr (8 waves, 2m x 4o). Block: b, 64 dst, 128 o, K-half.
#define ASZ 4096          // shorts per A buffer (8KB), x2
#define BSZ (128 * 64)    // shorts per B buffer (16KB), x4
__global__ __launch_bounds__(512, 4) void k2_gemm(const float* __restrict__ adj,
                                                  const unsigned short* __restrict__ ft,
                                                  float* __restrict__ pout,
                                                  float* __restrict__ dpart) {
  __shared__ __align__(16) unsigned short Alds[2 * ASZ];  // 16KB
  __shared__ __align__(16) unsigned short Blds[4 * BSZ];  // 64KB

  int bid = blockIdx.x;
  int b = bid & 7;                     // XCD pin (balanced: each XCD streams adj[b])
  int o0 = ((bid >> 3) & 1) * 128;     // 2 o-tiles
  int kc = (bid >> 4) & 1;             // split-K half
  int dst0 = (bid >> 5) * 64;          // 16 dst-tiles

  int t = threadIdx.x, l = t & 63, w = t >> 6;     // 8 waves
  int lr = l & 15, lg = l >> 4;
  int wm = w >> 2, wo = w & 3;                     // wave -> (dst-half, o-quarter)

  // A-staging (coalesced): thread -> dst_l (0..63), r-half, 2 src rows (sA, sA+4)
  int dst_l = (t >> 1) & 63;
  int rh = (t & 1) * 4;
  int sA = t >> 7;                     // 0..3
  // B-staging: pre-swizzled source chunk
  int csw = (l & 7) ^ (l >> 3);

  const size_t adj_b = (size_t)b << 23;
  const unsigned short* ftb = ft + ((size_t)b << 21);
  const int src_base = kc * 512;

  float dsum = 0.f;
  floatx4 acc[2][2] = {};
  float4 avA[2], avB[2];

  auto A_load = [&](int kt, float4* v) {
#pragma unroll
    for (int j = 0; j < 2; ++j) {
      int src = src_base + kt * 8 + sA + j * 4;
      v[j] = *(const float4*)(adj + adj_b + ((size_t)src << 13)
                              + ((size_t)(dst0 + dst_l) << 3) + rh);
    }
  };
  auto A_store = [&](int abuf, const float4* v) {
#pragma unroll
    for (int j = 0; j < 2; ++j) {
      int src_l = sA + j * 4;
      float4 q = v[j];
      dsum += q.x + q.y + q.z + q.w;
      ushortx4 h;
      h[0] = f2bf(q.x); h[1] = f2bf(q.y); h[2] = f2bf(q.z); h[3] = f2bf(q.w);
      int slot = src_l ^ (dst_l & 7);
      *(ushortx4*)&Alds[abuf * ASZ + dst_l * 64 + slot * 8 + rh] = h;
    }
  };
  auto B_stage = [&](int kt, int buf) {            // 2 gload16/wave, rows w*16..+15
    int kbase = (src_base + kt * 8) * 8;
#pragma unroll
    for (int i = 0; i < 2; ++i) {
      int orow = w * 16 + i * 8 + (l >> 3);
      const unsigned short* g = ftb + ((size_t)(o0 + orow) << 13) + kbase + (csw << 3);
      gload16(g, &Blds[buf * BSZ + (w * 16 + i * 8) * 64]);
    }
  };
  auto compute = [&](int bbuf, int abuf) {
#pragma unroll
    for (int s = 0; s < 2; ++s) {
      int slotbase = s * 4 + lg;
      shortx8 af[2], bfr[2];
#pragma unroll
      for (int mi = 0; mi < 2; ++mi) {
        int arow = wm * 32 + mi * 16 + lr;
        af[mi] = *(const shortx8*)&Alds[abuf * ASZ + arow * 64 + ((slotbase ^ (arow & 7)) << 3)];
      }
#pragma unroll
      for (int ni = 0; ni < 2; ++ni) {
        int brow = wo * 32 + ni * 16 + lr;
        bfr[ni] = *(const shortx8*)&Blds[bbuf * BSZ + brow * 64 + ((slotbase ^ (brow & 7)) << 3)];
      }
#pragma unroll
      for (int mi = 0; mi < 2; ++mi)
#pragma unroll
        for (int ni = 0; ni < 2; ++ni)
          acc[mi][ni] = __builtin_amdgcn_mfma_f32_16x16x32_bf16(af[mi], bfr[ni], acc[mi][ni], 0, 0, 0);
    }
  };

// step kt: stage B(kt+3)->STG; ds_write A(kt+1) (AVx, loaded step kt-2) -> abuf ABN;
//          reload AVx with A(kt+3); compute(CUR, ABC); counted fence + barrier.
#define STEP(kt, CUR, STG, ABN, ABC, AVx, ISS, STA, FN)                \
  {                                                                    \
    if (ISS) B_stage((kt) + 3, STG);                                   \
    if (STA) A_store(ABN, AVx);                                        \
    if (ISS) A_load((kt) + 3, AVx);                                    \
    compute(CUR, ABC);                                                 \
    if (FN >= 0) {                                                     \
      __builtin_amdgcn_sched_barrier(0);                               \
      if (FN == 8)      asm volatile("s_waitcnt vmcnt(8) lgkmcnt(0)" ::: "memory"); \
      else if (FN == 4) asm volatile("s_waitcnt vmcnt(4) lgkmcnt(0)" ::: "memory"); \
      else              asm volatile("s_waitcnt vmcnt(0) lgkmcnt(0)" ::: "memory"); \
      __builtin_amdgcn_s_barrier();                                    \
      __builtin_amdgcn_sched_barrier(0);                               \
    }                                                                  \
  }

  // ---- prologue: B0,B1,B2 staged; A0 stored->abuf0; avA=A(1), avB=A(2) ----
  B_stage(0, 0);
  B_stage(1, 1);
  B_stage(2, 2);
  A_load(0, avA);
  A_store(0, avA);                     // implicit wait on A0 (prologue-only drain)
  A_load(1, avA);
  A_load(2, avB);
  asm volatile("s_waitcnt vmcnt(0) lgkmcnt(0)" ::: "memory");
  __builtin_amdgcn_s_barrier();
  __builtin_amdgcn_sched_barrier(0);

  // ---- main loop: kt 0..59, 4-step macro (buf period 4; av/abuf parity 2) ----
  for (int kt0 = 0; kt0 < 60; kt0 += 4) {
    STEP(kt0 + 0, 0, 3, 1, 0, avA, 1, 1, 8);
    STEP(kt0 + 1, 1, 0, 0, 1, avB, 1, 1, 8);
    STEP(kt0 + 2, 2, 1, 1, 0, avA, 1, 1, 8);
    STEP(kt0 + 3, 3, 2, 0, 1, avB, 1, 1, 8);
  }
  // ---- tail: kt 60..63 ----
  STEP(60, 0, 3, 1, 0, avA, 1, 1, 8);   // issues B(63)/A(63); keeps {59,60}
  STEP(61, 1, 0, 0, 1, avB, 0, 1, 4);   // stores A(62); drains batch 59
  STEP(62, 2, 0, 1, 0, avA, 0, 1, 0);   // stores A(63); drains batch 60
  STEP(63, 3, 0, 0, 1, avB, 0, 0, -1);  // compute only
#undef STEP
  __syncthreads();                     // protect Alds overlay

  // ---- denom reduction (deterministic): 8 partials per dst row ----
  float* dsf = (float*)Alds;
  dsf[t] = dsum;
  __syncthreads();
  if (t < 64) {
    float s = 0.f;
#pragma unroll
    for (int sl = 0; sl < 4; ++sl) {
      s += dsf[sl * 128 + t * 2];
      s += dsf[sl * 128 + t * 2 + 1];
    }
    dpart[kc * 8192 + (b << 10) + dst0 + t] = s;
  }

  // ---- write partials ----
#pragma unroll
  for (int mi = 0; mi < 2; ++mi) {
#pragma unroll
    for (int reg = 0; reg < 4; ++reg) {
      int row = dst0 + wm * 32 + mi * 16 + lg * 4 + reg;
#pragma unroll
      for (int ni = 0; ni < 2; ++ni) {
        int col = o0 + wo * 32 + ni * 16 + lr;
        pout[(size_t)kc * 2097152 + (((size_t)b << 10) + row) * 256 + col] = acc[mi][ni][reg];
      }
    }
  }
}

// ---------------- kernel 3: split-K reduce + normalize ----------------
__global__ __launch_bounds__(256) void k3_reduce(const float* __restrict__ pout,
                                                 const float* __restrict__ dpart,
                                                 float* __restrict__ outp) {
  int bid = blockIdx.x;              // b*1024 + dst
  size_t base = (size_t)bid * 256 + threadIdx.x;
  float v = pout[base] + pout[2097152 + base];
  float d = dpart[bid] + dpart[8192 + bid];
  outp[base] = v / fmaxf(d, 1e-16f);
}

// ---------------- launch ----------------
extern "C" void kernel_launch(void* const* d_in, const int* in_sizes, int n_in,
                              void* d_out, int out_size, void* d_ws, size_t ws_size,
                              hipStream_t stream) {
  const float* x   = (const float*)d_in[0];
  const float* adj = (const float*)d_in[1];
  const float* w   = (const float*)d_in[2];
  float* out = (float*)d_out;

  char* ws = (char*)d_ws;
  unsigned short* ft  = (unsigned short*)(ws);              // 32 MB
  unsigned short* xbf = (unsigned short*)(ws + 33554432);   //  4 MB
  unsigned short* wt  = (unsigned short*)(ws + 37748736);   //  1 MB
  float* pout  = (float*)(ws + 38797312);                   // 16 MB
  float* dpart = (float*)(ws + 55574528);                   // 64 KB

  prep_xw<<<3072, 256, 0, stream>>>(x, w, xbf, wt);
  k1_gemm<<<1024, 256, 0, stream>>>(xbf, wt, ft);
  k2_gemm<<<512, 512, 0, stream>>>(adj, ft, pout, dpart);
  k3_reduce<<<8192, 256, 0, stream>>>(pout, dpart, out);
}